// Round 5
// baseline (974.595 us; speedup 1.0000x reference)
//
#include <hip/hip_runtime.h>

#define FDIM 64
#define NSDIM 64
#define TREP 3
#define EPSV 1e-8f

// ============================================================================
// Register-tile GEMM family: one lane owns one output row (64 f32 accumulators
// in VGPRs). X row loaded per-lane as float4 (VMEM); W rows read via wave-
// uniform pointers -> scalar loads (SGPR). No LDS-pipe traffic.
// ============================================================================

// ---------- G matrix: G[t,r,:] = normf(r)*(X[r]@W[t]+b[t]) - |X[r]@W[t]+b[t]|*X[r] ----------
// (trans / normf / normt never materialized; mask test becomes dot(G,f_d) > 0)
__global__ __launch_bounds__(256) void gmat_k(const float* __restrict__ X,
                                              const float* __restrict__ W,
                                              const float* __restrict__ B,
                                              float* __restrict__ G, int nN)
{
  const int t    = blockIdx.y;
  const int lane = threadIdx.x & 63;
  const int wib  = threadIdx.x >> 6;
  const int row  = blockIdx.x * 256 + wib * 64 + lane;
  const float* __restrict__ Wt = W + (size_t)t * FDIM * FDIM;
  const float* __restrict__ Bt = B + t * FDIM;
  float acc[FDIM];
#pragma unroll
  for (int c = 0; c < FDIM; ++c) acc[c] = Bt[c];
  if (row >= nN) return;
  const float4* __restrict__ xr = (const float4*)(X + (size_t)row * FDIM);
  float ss = 0.f;
#pragma unroll 2
  for (int kk = 0; kk < FDIM / 4; ++kk) {
    const float4 xv = xr[kk];
    ss = fmaf(xv.x, xv.x, fmaf(xv.y, xv.y, fmaf(xv.z, xv.z, fmaf(xv.w, xv.w, ss))));
    const float* __restrict__ w0 = Wt + (kk * 4 + 0) * FDIM;
    const float* __restrict__ w1 = Wt + (kk * 4 + 1) * FDIM;
    const float* __restrict__ w2 = Wt + (kk * 4 + 2) * FDIM;
    const float* __restrict__ w3 = Wt + (kk * 4 + 3) * FDIM;
#pragma unroll
    for (int c = 0; c < FDIM; ++c) acc[c] = fmaf(xv.x, w0[c], acc[c]);
#pragma unroll
    for (int c = 0; c < FDIM; ++c) acc[c] = fmaf(xv.y, w1[c], acc[c]);
#pragma unroll
    for (int c = 0; c < FDIM; ++c) acc[c] = fmaf(xv.z, w2[c], acc[c]);
#pragma unroll
    for (int c = 0; c < FDIM; ++c) acc[c] = fmaf(xv.w, w3[c], acc[c]);
  }
  float sq = 0.f;
#pragma unroll
  for (int c = 0; c < FDIM; ++c) sq = fmaf(acc[c], acc[c], sq);
  const float nf = fmaxf(sqrtf(ss), EPSV);
  const float na = fmaxf(sqrtf(sq), EPSV);
  float* __restrict__ grow = G + ((size_t)t * nN + row) * FDIM;
#pragma unroll
  for (int c4 = 0; c4 < FDIM / 4; ++c4) {
    const float4 xv = xr[c4];
    ((float4*)grow)[c4] = make_float4(
        fmaf(nf, acc[4 * c4 + 0], -na * xv.x),
        fmaf(nf, acc[4 * c4 + 1], -na * xv.y),
        fmaf(nf, acc[4 * c4 + 2], -na * xv.z),
        fmaf(nf, acc[4 * c4 + 3], -na * xv.w));
  }
}

// ---------- generic: out[r,:] = act(X[r,:]) @ W ; fused scaled copy ----------
template<bool RELU_IN>
__global__ __launch_bounds__(256) void gemm_k(const float* __restrict__ X,
                                              const float* __restrict__ W,
                                              float* __restrict__ out, int rows,
                                              float* __restrict__ scaled,
                                              const float* __restrict__ dinv, int nScaled)
{
  const int lane = threadIdx.x & 63;
  const int wib  = threadIdx.x >> 6;
  const int row  = blockIdx.x * 256 + wib * 64 + lane;
  if (row >= rows) return;
  float acc[FDIM];
#pragma unroll
  for (int c = 0; c < FDIM; ++c) acc[c] = 0.f;
  const float4* __restrict__ xr = (const float4*)(X + (size_t)row * FDIM);
#pragma unroll 2
  for (int kk = 0; kk < FDIM / 4; ++kk) {
    float4 xv = xr[kk];
    if (RELU_IN) {
      xv.x = fmaxf(xv.x, 0.f); xv.y = fmaxf(xv.y, 0.f);
      xv.z = fmaxf(xv.z, 0.f); xv.w = fmaxf(xv.w, 0.f);
    }
    const float* __restrict__ w0 = W + (kk * 4 + 0) * FDIM;
    const float* __restrict__ w1 = W + (kk * 4 + 1) * FDIM;
    const float* __restrict__ w2 = W + (kk * 4 + 2) * FDIM;
    const float* __restrict__ w3 = W + (kk * 4 + 3) * FDIM;
#pragma unroll
    for (int c = 0; c < FDIM; ++c) acc[c] = fmaf(xv.x, w0[c], acc[c]);
#pragma unroll
    for (int c = 0; c < FDIM; ++c) acc[c] = fmaf(xv.y, w1[c], acc[c]);
#pragma unroll
    for (int c = 0; c < FDIM; ++c) acc[c] = fmaf(xv.z, w2[c], acc[c]);
#pragma unroll
    for (int c = 0; c < FDIM; ++c) acc[c] = fmaf(xv.w, w3[c], acc[c]);
  }
  float* __restrict__ orow = out + (size_t)row * FDIM;
#pragma unroll
  for (int c4 = 0; c4 < FDIM / 4; ++c4)
    ((float4*)orow)[c4] = make_float4(acc[4 * c4], acc[4 * c4 + 1],
                                      acc[4 * c4 + 2], acc[4 * c4 + 3]);
  if (scaled != nullptr && row < nScaled) {
    const float dv = dinv[row];
    float* __restrict__ srow = scaled + (size_t)row * FDIM;
#pragma unroll
    for (int c4 = 0; c4 < FDIM / 4; ++c4)
      ((float4*)srow)[c4] = make_float4(acc[4 * c4] * dv, acc[4 * c4 + 1] * dv,
                                        acc[4 * c4 + 2] * dv, acc[4 * c4 + 3] * dv);
  }
}

// ---------- logits + per-lane argmax + H count ----------
__global__ __launch_bounds__(256) void logits_k(const float* __restrict__ X,
                                                const float* __restrict__ W,
                                                const float* __restrict__ B,
                                                float* __restrict__ H,
                                                int rows, int nN)
{
  const int lane = threadIdx.x & 63;
  const int wib  = threadIdx.x >> 6;
  const int row  = blockIdx.x * 256 + wib * 64 + lane;
  float acc[NSDIM];
#pragma unroll
  for (int c = 0; c < NSDIM; ++c) acc[c] = B[c];
  if (row >= rows) return;
  const float4* __restrict__ xr = (const float4*)(X + (size_t)row * FDIM);
#pragma unroll 2
  for (int kk = 0; kk < FDIM / 4; ++kk) {
    float4 xv = xr[kk];
    xv.x = fmaxf(xv.x, 0.f); xv.y = fmaxf(xv.y, 0.f);
    xv.z = fmaxf(xv.z, 0.f); xv.w = fmaxf(xv.w, 0.f);
    const float* __restrict__ w0 = W + (kk * 4 + 0) * NSDIM;
    const float* __restrict__ w1 = W + (kk * 4 + 1) * NSDIM;
    const float* __restrict__ w2 = W + (kk * 4 + 2) * NSDIM;
    const float* __restrict__ w3 = W + (kk * 4 + 3) * NSDIM;
#pragma unroll
    for (int c = 0; c < NSDIM; ++c) acc[c] = fmaf(xv.x, w0[c], acc[c]);
#pragma unroll
    for (int c = 0; c < NSDIM; ++c) acc[c] = fmaf(xv.y, w1[c], acc[c]);
#pragma unroll
    for (int c = 0; c < NSDIM; ++c) acc[c] = fmaf(xv.z, w2[c], acc[c]);
#pragma unroll
    for (int c = 0; c < NSDIM; ++c) acc[c] = fmaf(xv.w, w3[c], acc[c]);
  }
  float bv = acc[0]; int bi = 0;
#pragma unroll
  for (int c = 1; c < NSDIM; ++c)
    if (acc[c] > bv) { bv = acc[c]; bi = c; }   // strict > : first-index tiebreak
  int v = row;
  while (v >= nN) v -= nN;
  atomicAdd(&H[(size_t)v * NSDIM + bi], 1.f);
}

// ---------- dots = (features @ hyperT) * 0.125, tiled 4x ----------
__global__ __launch_bounds__(256) void dots_k(const float* __restrict__ X,
                                              const float* __restrict__ WT,
                                              float* __restrict__ out2, int nN)
{
  const int lane = threadIdx.x & 63;
  const int wib  = threadIdx.x >> 6;
  const int row  = blockIdx.x * 256 + wib * 64 + lane;
  if (row >= nN) return;
  float acc[NSDIM];
#pragma unroll
  for (int c = 0; c < NSDIM; ++c) acc[c] = 0.f;
  const float4* __restrict__ xr = (const float4*)(X + (size_t)row * FDIM);
#pragma unroll 2
  for (int kk = 0; kk < FDIM / 4; ++kk) {
    const float4 xv = xr[kk];
    const float* __restrict__ w0 = WT + (kk * 4 + 0) * NSDIM;
    const float* __restrict__ w1 = WT + (kk * 4 + 1) * NSDIM;
    const float* __restrict__ w2 = WT + (kk * 4 + 2) * NSDIM;
    const float* __restrict__ w3 = WT + (kk * 4 + 3) * NSDIM;
#pragma unroll
    for (int c = 0; c < NSDIM; ++c) acc[c] = fmaf(xv.x, w0[c], acc[c]);
#pragma unroll
    for (int c = 0; c < NSDIM; ++c) acc[c] = fmaf(xv.y, w1[c], acc[c]);
#pragma unroll
    for (int c = 0; c < NSDIM; ++c) acc[c] = fmaf(xv.z, w2[c], acc[c]);
#pragma unroll
    for (int c = 0; c < NSDIM; ++c) acc[c] = fmaf(xv.w, w3[c], acc[c]);
  }
#pragma unroll
  for (int c = 0; c < NSDIM; ++c) acc[c] *= 0.125f;
#pragma unroll
  for (int b = 0; b < 4; ++b) {
    float* __restrict__ orow = out2 + ((size_t)b * nN + row) * NSDIM;
#pragma unroll
    for (int c4 = 0; c4 < NSDIM / 4; ++c4)
      ((float4*)orow)[c4] = make_float4(acc[4 * c4], acc[4 * c4 + 1],
                                        acc[4 * c4 + 2], acc[4 * c4 + 3]);
  }
}

// ============================================================================
// Graph kernels
// ============================================================================

// ---------- src-CSR: counts ----------
__global__ void cntS_k(const int* __restrict__ src, int* __restrict__ cntS, int nE)
{
  for (int e = blockIdx.x * blockDim.x + threadIdx.x; e < nE;
       e += gridDim.x * blockDim.x)
    atomicAdd(&cntS[src[e]], 1);
}

// ---------- src-CSR: fill (slots hold dst; mask bits added later) ----------
__global__ void fillS_k(const int* __restrict__ src, const int* __restrict__ dst,
                        int* __restrict__ cursorS, unsigned* __restrict__ slotsS, int nE)
{
  for (int e = blockIdx.x * blockDim.x + threadIdx.x; e < nE;
       e += gridDim.x * blockDim.x) {
    int pos = atomicAdd(&cursorS[src[e]], 1);
    slotsS[pos] = (unsigned)dst[e];
  }
}

// ---------- exclusive prefix scan (single block) ----------
__global__ void scan_k(const int* __restrict__ cnt, int* __restrict__ rowoff,
                       int* __restrict__ cursor, int nN)
{
  __shared__ int s[256];
  const int chunk = (nN + 255) / 256;
  const int lo = threadIdx.x * chunk;
  const int hi = min(lo + chunk, nN);
  int sum = 0;
  for (int i = lo; i < hi; ++i) sum += cnt[i];
  s[threadIdx.x] = sum;
  __syncthreads();
  if (threadIdx.x == 0) {
    int run = 0;
    for (int i = 0; i < 256; ++i) { int t = s[i]; s[i] = run; run += t; }
    rowoff[nN] = run;
  }
  __syncthreads();
  int run = s[threadIdx.x];
  for (int i = lo; i < hi; ++i) {
    rowoff[i] = run;
    cursor[i] = run;
    run += cnt[i];
  }
}

// ---------- mask + degree counts: wave = 4 edges of one source, 16 lanes each ----------
// mask bit t set iff dot(G[t][s], f[d]) > 0. Writes mask into slotsS bits 20+.
__global__ void mask_cnt_k(const int* __restrict__ rowoffS, unsigned* __restrict__ slotsS,
                           const float* __restrict__ G, const float* __restrict__ f,
                           int* __restrict__ cnt, int nN)
{
  const int lane = threadIdx.x & 63;
  const int wib  = threadIdx.x >> 6;
  const int wpb  = blockDim.x >> 6;
  const int i = lane & 15;   // component quad index
  const int g = lane >> 4;   // edge sub-slot within wave
  const float4* __restrict__ G4 = (const float4*)G;
  const float4* __restrict__ f4 = (const float4*)f;
  for (int s = blockIdx.x * wpb + wib; s < nN; s += gridDim.x * wpb) {
    const int start = rowoffS[s], end = rowoffS[s + 1];
    if (start == end) continue;
    const float4 g0 = G4[((size_t)0 * nN + s) * 16 + i];
    const float4 g1 = G4[((size_t)1 * nN + s) * 16 + i];
    const float4 g2 = G4[((size_t)2 * nN + s) * 16 + i];
    for (int base = start; base < end; base += 4) {
      const int e = base + g;
      const bool valid = e < end;
      const int ee = valid ? e : start;
      const unsigned d = slotsS[ee] & 0xFFFFFu;
      const float4 fv = f4[(size_t)d * 16 + i];
      float p0 = fmaf(fv.x, g0.x, fmaf(fv.y, g0.y, fmaf(fv.z, g0.z, fv.w * g0.w)));
      float p1 = fmaf(fv.x, g1.x, fmaf(fv.y, g1.y, fmaf(fv.z, g1.z, fv.w * g1.w)));
      float p2 = fmaf(fv.x, g2.x, fmaf(fv.y, g2.y, fmaf(fv.z, g2.z, fv.w * g2.w)));
#pragma unroll
      for (int o = 8; o > 0; o >>= 1) {
        p0 += __shfl_xor(p0, o);
        p1 += __shfl_xor(p1, o);
        p2 += __shfl_xor(p2, o);
      }
      if (i == 0 && valid) {
        unsigned m = (p0 > 0.f ? 1u : 0u) | (p1 > 0.f ? 2u : 0u) | (p2 > 0.f ? 4u : 0u);
        if (m) slotsS[e] = d | (m << 20);
        atomicAdd(&cnt[d], 1);
        if (m & 1u) atomicAdd(&cnt[nN + d], 1);
        if (m & 2u) atomicAdd(&cnt[2 * nN + d], 1);
        if (m & 4u) atomicAdd(&cnt[3 * nN + d], 1);
      }
    }
  }
}

// ---------- dst-CSR fill from src-CSR slots (wave per source, lane per slot) ----------
__global__ void fillD_k(const int* __restrict__ rowoffS, const unsigned* __restrict__ slotsS,
                        int* __restrict__ cursorD, unsigned* __restrict__ csrD, int nN)
{
  const int lane = threadIdx.x & 63;
  const int wib  = threadIdx.x >> 6;
  const int wpb  = blockDim.x >> 6;
  for (int s = blockIdx.x * wpb + wib; s < nN; s += gridDim.x * wpb) {
    const int start = rowoffS[s], end = rowoffS[s + 1];
    for (int pos = start + lane; pos < end; pos += 64) {
      const unsigned v = slotsS[pos];
      const unsigned d = v & 0xFFFFFu;
      const unsigned m = v >> 20;
      int p = atomicAdd(&cursorD[d], 1);
      csrD[p] = (unsigned)s | (m << 20);
    }
  }
}

// ---------- dinv from int counts ----------
__global__ void dinv_k(const int* __restrict__ cnt, float* __restrict__ dinv, int nN)
{
  int i = blockIdx.x * blockDim.x + threadIdx.x;
  int tot = 4 * nN;
  if (i < tot) {
    float base = (i < nN) ? 1.f : 2.f;  // block0: +self ; replicas: +identity edge +self
    dinv[i] = 1.f / sqrtf((float)cnt[i] + base);
  }
}

// ---------- fused CSR gather + GCN finish (wave per destination node) ----------
template<bool L0, bool RELU>
__global__ void gather_finish_k(const int* __restrict__ rowoff, const unsigned* __restrict__ csr,
                                const float* __restrict__ xws, const float* __restrict__ xw,
                                const float* __restrict__ dinv, const float* __restrict__ bias,
                                float* __restrict__ out, int nN)
{
  const int lane = threadIdx.x & 63;
  const int wib  = threadIdx.x >> 6;
  const int wpb  = blockDim.x >> 6;
  const float b = bias[lane];
  for (int d = blockIdx.x * wpb + wib; d < nN; d += gridDim.x * wpb) {
    const int start = rowoff[d], end = rowoff[d + 1];
    float a0 = 0.f, a1 = 0.f, a2 = 0.f, a3 = 0.f;
    for (int base = start; base < end; base += 64) {
      const int nrem = end - base;
      unsigned p = (lane < nrem) ? csr[base + lane] : 0u;
      const int cntj = nrem < 64 ? nrem : 64;
      for (int j = 0; j < cntj; ++j) {
        const unsigned pj = (unsigned)__shfl((int)p, j);
        const int s = (int)(pj & 0xFFFFFu);
        const unsigned mk = pj >> 20;
        const float v = xws[(size_t)s * FDIM + lane];
        a0 += v;
        if (mk & 1u) a1 += v;
        if (mk & 2u) a2 += v;
        if (mk & 4u) a3 += v;
      }
    }
    const float di0 = dinv[d];
    const float xs  = xws[(size_t)d * FDIM + lane];
    const float xb0 = xw[(size_t)d * FDIM + lane];

    float r0 = (a0 + xs) * di0 + b;
    if (RELU) r0 = fmaxf(r0, 0.f);
    out[(size_t)d * FDIM + lane] = r0;

#pragma unroll
    for (int t = 1; t <= 3; ++t) {
      const float at = (t == 1) ? a1 : (t == 2) ? a2 : a3;
      const float dit = dinv[t * nN + d];
      const float self = L0 ? xb0 : xw[((size_t)t * nN + d) * FDIM + lane];
      float r = (at + xs + self * dit) * dit + b;
      if (RELU) r = fmaxf(r, 0.f);
      out[((size_t)t * nN + d) * FDIM + lane] = r;
    }
  }
}

// ---------- hyper[j,:] += x2_b0[i,:] where H[i,j] > 0 (LDS-accumulated) ----------
__global__ void hyper_k(const float* __restrict__ H, const float* __restrict__ x2,
                        float* __restrict__ hyper, int nN)
{
  __shared__ float hl[NSDIM * FDIM];
  for (int i = threadIdx.x; i < NSDIM * FDIM; i += blockDim.x) hl[i] = 0.f;
  __syncthreads();
  const int lane = threadIdx.x & 63;
  const int wib  = threadIdx.x >> 6;
  const int wpb  = blockDim.x >> 6;
  for (int i = blockIdx.x * wpb + wib; i < nN; i += gridDim.x * wpb) {
    float hv = H[(size_t)i * NSDIM + lane];
    unsigned long long ball = __ballot(hv > 0.f);
    float x = x2[(size_t)i * FDIM + lane];
    while (ball) {
      int j = __ffsll((unsigned long long)ball) - 1;
      ball &= ball - 1;
      atomicAdd(&hl[j * FDIM + lane], x);
    }
  }
  __syncthreads();
  for (int i = threadIdx.x; i < NSDIM * FDIM; i += blockDim.x) {
    float v = hl[i];
    if (v != 0.f) atomicAdd(&hyper[i], v);
  }
}

// ---------- hyper -> out1 + transposed copy for dots ----------
__global__ void hfin_k(const float* __restrict__ hyper, float* __restrict__ out1,
                       float* __restrict__ hyperT)
{
  int idx = blockIdx.x * blockDim.x + threadIdx.x;
  if (idx < NSDIM * FDIM) {
    float v = hyper[idx];
    out1[idx] = v;
    int j = idx >> 6, k = idx & 63;
    hyperT[k * NSDIM + j] = v;
  }
}

// ---------- per-column histogram -> max + softmax denominator (H in {0..4}) ----------
__global__ void colstats_k(const float* __restrict__ H, float* __restrict__ cmax,
                           float* __restrict__ cden, int nN)
{
  __shared__ int s[8];
  const int j = blockIdx.x;
  if (threadIdx.x < 8) s[threadIdx.x] = 0;
  __syncthreads();
  int c[5] = {0, 0, 0, 0, 0};
  for (int i = threadIdx.x; i < nN; i += blockDim.x) {
    int v = (int)H[(size_t)i * NSDIM + j];
    c[v]++;
  }
#pragma unroll
  for (int k = 0; k < 5; ++k) atomicAdd(&s[k], c[k]);
  __syncthreads();
  if (threadIdx.x == 0) {
    int m = 0;
#pragma unroll
    for (int k = 0; k < 5; ++k) if (s[k] > 0) m = k;
    float den = 0.f;
#pragma unroll
    for (int k = 0; k < 5; ++k) den += (float)s[k] * expf((float)(k - m));
    cmax[j] = (float)m;
    cden[j] = den;
  }
}

__global__ void hsoft_k(const float* __restrict__ H, const float* __restrict__ cmax,
                        const float* __restrict__ cden, float* __restrict__ out0, int nN)
{
  int idx = blockIdx.x * blockDim.x + threadIdx.x;
  int tot = nN * NSDIM;
  if (idx < tot) {
    int j = idx & (NSDIM - 1);
    out0[idx] = expf(H[idx] - cmax[j]) / cden[j];
  }
}

// ---------- host ----------
extern "C" void kernel_launch(void* const* d_in, const int* in_sizes, int n_in,
                              void* d_out, int out_size, void* d_ws, size_t ws_size,
                              hipStream_t stream)
{
  const int* edge_index = (const int*)d_in[0];
  const float* features = (const float*)d_in[1];
  const float* W_lin    = (const float*)d_in[2];
  const float* b_lin    = (const float*)d_in[3];
  const float* gcn0_W   = (const float*)d_in[4];
  const float* gcn0_b   = (const float*)d_in[5];
  const float* gcn1_W   = (const float*)d_in[6];
  const float* gcn1_b   = (const float*)d_in[7];
  const float* lin1_W   = (const float*)d_in[8];
  const float* lin1_b   = (const float*)d_in[9];

  const int E = in_sizes[0] / 2;
  const int N = in_sizes[1] / FDIM;

  const int* src = edge_index;
  const int* dst = edge_index + E;

  // workspace layout
  float* ws    = (float*)d_ws;
  float* G     = ws;                                   // 3*N*F (dead after mask_cnt)
  int*   cnt   = (int*)(G + (size_t)TREP * N * FDIM);  // 4N
  float* dinv  = (float*)(cnt + (size_t)4 * N);        // 4N
  int*   cntS  = (int*)(dinv + (size_t)4 * N);         // N (also cursorS)
  int*   rowoffS = cntS + N;                           // N+64
  unsigned* slotsS = (unsigned*)(rowoffS + N + 64);    // E
  float* xw0   = (float*)(slotsS + E);                 // N*F
  float* bufA  = xw0 + (size_t)N * FDIM;               // 4N*F (x1 -> x2)
  float* bufB  = bufA + (size_t)4 * N * FDIM;          // 4N*F (xw1)
  float* Harr  = bufB + (size_t)4 * N * FDIM;          // N*NS
  float* hyper = Harr + (size_t)N * NSDIM;             // NS*F
  float* cmax  = hyper + NSDIM * FDIM;                 // NS
  float* cden  = cmax + NSDIM;                         // NS
  float* hyperT = cden + NSDIM;                        // NS*F

  // dst-CSR + scaled message table alias the (dead-after-mask) G region
  int* rowoffD     = (int*)G;                          // N+64
  int* cursorD     = rowoffD + (N + 64);               // N
  unsigned* csrD   = (unsigned*)(cursorD + N);         // E
  float* xws       = (float*)(csrD + E);               // N*F
  // (2N+64+E) ints + N*F floats = ~16.4 MB < G's 38.4 MB

  float* out0 = (float*)d_out;             // H_soft (N,NS)
  float* out1 = out0 + (size_t)N * NSDIM;  // hyper (NS,F)
  float* out2 = out1 + NSDIM * FDIM;       // dots (4N,NS)

  const int BLK = 256;
  const int WPB = BLK / 64;
  auto wgrid = [](int items, int wpb) { return (items + wpb - 1) / wpb; };
  auto tgrid = [](int rows) { return (rows + 255) / 256; };

  // zero accumulators
  hipMemsetAsync(cnt, 0, (size_t)4 * N * sizeof(int), stream);
  hipMemsetAsync(cntS, 0, (size_t)N * sizeof(int), stream);
  hipMemsetAsync(Harr, 0, (size_t)N * NSDIM * sizeof(float), stream);
  hipMemsetAsync(hyper, 0, (size_t)NSDIM * FDIM * sizeof(float), stream);

  // 1) src-CSR build (independent of G)
  cntS_k<<<1024, BLK, 0, stream>>>(src, cntS, E);
  scan_k<<<1, 256, 0, stream>>>(cntS, rowoffS, cntS, N);   // cntS becomes cursorS
  fillS_k<<<1024, BLK, 0, stream>>>(src, dst, cntS, slotsS, E);

  // 2) G = normf*trans - normt*f  (trans/norms never materialized)
  {
    dim3 g(tgrid(N), TREP);
    gmat_k<<<g, BLK, 0, stream>>>(features, W_lin, b_lin, G, N);
  }

  // 3) mask + degree counts (4 edges/wave, 16-lane groups)
  mask_cnt_k<<<wgrid(N, WPB), BLK, 0, stream>>>(rowoffS, slotsS, G, features, cnt, N);

  // 4) dst-CSR build (G dead; rowoffD/cursorD/csrD/xws alias it)
  scan_k<<<1, 256, 0, stream>>>(cnt, rowoffD, cursorD, N);
  fillD_k<<<wgrid(N, WPB), BLK, 0, stream>>>(rowoffS, slotsS, cursorD, csrD, N);

  // 5) dinv
  dinv_k<<<(4 * N + BLK - 1) / BLK, BLK, 0, stream>>>(cnt, dinv, N);

  // 6) xw0 = relu(features) @ gcn0_W ; fused xws = xw0 * dinv0
  gemm_k<true><<<tgrid(N), BLK, 0, stream>>>(features, gcn0_W, xw0, N, xws, dinv, N);

  // 7) gcn0 gather+finish -> x1 (relu'd) in bufA
  gather_finish_k<true, true><<<wgrid(N, WPB), BLK, 0, stream>>>(
      rowoffD, csrD, xws, xw0, dinv, gcn0_b, bufA, N);

  // 8) xw1 = x1 @ gcn1_W (4N rows); fused xws = xw1(block0) * dinv0
  gemm_k<false><<<tgrid(4 * N), BLK, 0, stream>>>(bufA, gcn1_W, bufB, 4 * N, xws, dinv, N);

  // 9) gcn1 gather+finish -> x2 in bufA (no relu)
  gather_finish_k<false, false><<<wgrid(N, WPB), BLK, 0, stream>>>(
      rowoffD, csrD, xws, bufB, dinv, gcn1_b, bufA, N);

  // 10) logits + argmax -> H counts
  logits_k<<<tgrid(4 * N), BLK, 0, stream>>>(bufA, lin1_W, lin1_b, Harr, 4 * N, N);

  // 11) hyper (LDS-accumulated) + out1 + transpose
  hyper_k<<<128, BLK, 0, stream>>>(Harr, bufA, hyper, N);
  hfin_k<<<(NSDIM * FDIM + BLK - 1) / BLK, BLK, 0, stream>>>(hyper, out1, hyperT);

  // 12) H softmax over axis 0
  colstats_k<<<NSDIM, BLK, 0, stream>>>(Harr, cmax, cden, N);
  hsoft_k<<<(N * NSDIM + BLK - 1) / BLK, BLK, 0, stream>>>(Harr, cmax, cden, out0, N);

  // 13) dots
  dots_k<<<tgrid(N), BLK, 0, stream>>>(features, hyperT, out2, N);
}

// Round 6
// 753.064 us; speedup vs baseline: 1.2942x; 1.2942x over previous
//
#include <hip/hip_runtime.h>

#define FDIM 64
#define NSDIM 64
#define TREP 3
#define EPSV 1e-8f

// ============================================================================
// Register-tile GEMM family: one lane owns one output row (64 f32 accumulators
// in VGPRs). X row loaded per-lane as float4 (VMEM); W rows read via wave-
// uniform pointers -> scalar loads (SGPR). No LDS-pipe traffic.
// ============================================================================

// ---------- G matrix: G[t,r,:] = normf(r)*(X[r]@W[t]+b[t]) - |X[r]@W[t]+b[t]|*X[r] ----------
__global__ __launch_bounds__(256) void gmat_k(const float* __restrict__ X,
                                              const float* __restrict__ W,
                                              const float* __restrict__ B,
                                              float* __restrict__ G, int nN)
{
  const int t    = blockIdx.y;
  const int lane = threadIdx.x & 63;
  const int wib  = threadIdx.x >> 6;
  const int row  = blockIdx.x * 256 + wib * 64 + lane;
  const float* __restrict__ Wt = W + (size_t)t * FDIM * FDIM;
  const float* __restrict__ Bt = B + t * FDIM;
  float acc[FDIM];
#pragma unroll
  for (int c = 0; c < FDIM; ++c) acc[c] = Bt[c];
  if (row >= nN) return;
  const float4* __restrict__ xr = (const float4*)(X + (size_t)row * FDIM);
  float ss = 0.f;
#pragma unroll 2
  for (int kk = 0; kk < FDIM / 4; ++kk) {
    const float4 xv = xr[kk];
    ss = fmaf(xv.x, xv.x, fmaf(xv.y, xv.y, fmaf(xv.z, xv.z, fmaf(xv.w, xv.w, ss))));
    const float* __restrict__ w0 = Wt + (kk * 4 + 0) * FDIM;
    const float* __restrict__ w1 = Wt + (kk * 4 + 1) * FDIM;
    const float* __restrict__ w2 = Wt + (kk * 4 + 2) * FDIM;
    const float* __restrict__ w3 = Wt + (kk * 4 + 3) * FDIM;
#pragma unroll
    for (int c = 0; c < FDIM; ++c) acc[c] = fmaf(xv.x, w0[c], acc[c]);
#pragma unroll
    for (int c = 0; c < FDIM; ++c) acc[c] = fmaf(xv.y, w1[c], acc[c]);
#pragma unroll
    for (int c = 0; c < FDIM; ++c) acc[c] = fmaf(xv.z, w2[c], acc[c]);
#pragma unroll
    for (int c = 0; c < FDIM; ++c) acc[c] = fmaf(xv.w, w3[c], acc[c]);
  }
  float sq = 0.f;
#pragma unroll
  for (int c = 0; c < FDIM; ++c) sq = fmaf(acc[c], acc[c], sq);
  const float nf = fmaxf(sqrtf(ss), EPSV);
  const float na = fmaxf(sqrtf(sq), EPSV);
  float* __restrict__ grow = G + ((size_t)t * nN + row) * FDIM;
#pragma unroll
  for (int c4 = 0; c4 < FDIM / 4; ++c4) {
    const float4 xv = xr[c4];
    ((float4*)grow)[c4] = make_float4(
        fmaf(nf, acc[4 * c4 + 0], -na * xv.x),
        fmaf(nf, acc[4 * c4 + 1], -na * xv.y),
        fmaf(nf, acc[4 * c4 + 2], -na * xv.z),
        fmaf(nf, acc[4 * c4 + 3], -na * xv.w));
  }
}

// ---------- generic: out[r,:] = act(X[r,:]) @ W ; fused scaled copy ----------
template<bool RELU_IN>
__global__ __launch_bounds__(256) void gemm_k(const float* __restrict__ X,
                                              const float* __restrict__ W,
                                              float* __restrict__ out, int rows,
                                              float* __restrict__ scaled,
                                              const float* __restrict__ dinv, int nScaled)
{
  const int lane = threadIdx.x & 63;
  const int wib  = threadIdx.x >> 6;
  const int row  = blockIdx.x * 256 + wib * 64 + lane;
  if (row >= rows) return;
  float acc[FDIM];
#pragma unroll
  for (int c = 0; c < FDIM; ++c) acc[c] = 0.f;
  const float4* __restrict__ xr = (const float4*)(X + (size_t)row * FDIM);
#pragma unroll 2
  for (int kk = 0; kk < FDIM / 4; ++kk) {
    float4 xv = xr[kk];
    if (RELU_IN) {
      xv.x = fmaxf(xv.x, 0.f); xv.y = fmaxf(xv.y, 0.f);
      xv.z = fmaxf(xv.z, 0.f); xv.w = fmaxf(xv.w, 0.f);
    }
    const float* __restrict__ w0 = W + (kk * 4 + 0) * FDIM;
    const float* __restrict__ w1 = W + (kk * 4 + 1) * FDIM;
    const float* __restrict__ w2 = W + (kk * 4 + 2) * FDIM;
    const float* __restrict__ w3 = W + (kk * 4 + 3) * FDIM;
#pragma unroll
    for (int c = 0; c < FDIM; ++c) acc[c] = fmaf(xv.x, w0[c], acc[c]);
#pragma unroll
    for (int c = 0; c < FDIM; ++c) acc[c] = fmaf(xv.y, w1[c], acc[c]);
#pragma unroll
    for (int c = 0; c < FDIM; ++c) acc[c] = fmaf(xv.z, w2[c], acc[c]);
#pragma unroll
    for (int c = 0; c < FDIM; ++c) acc[c] = fmaf(xv.w, w3[c], acc[c]);
  }
  float* __restrict__ orow = out + (size_t)row * FDIM;
#pragma unroll
  for (int c4 = 0; c4 < FDIM / 4; ++c4)
    ((float4*)orow)[c4] = make_float4(acc[4 * c4], acc[4 * c4 + 1],
                                      acc[4 * c4 + 2], acc[4 * c4 + 3]);
  if (scaled != nullptr && row < nScaled) {
    const float dv = dinv[row];
    float* __restrict__ srow = scaled + (size_t)row * FDIM;
#pragma unroll
    for (int c4 = 0; c4 < FDIM / 4; ++c4)
      ((float4*)srow)[c4] = make_float4(acc[4 * c4] * dv, acc[4 * c4 + 1] * dv,
                                        acc[4 * c4 + 2] * dv, acc[4 * c4 + 3] * dv);
  }
}

// ---------- logits + per-lane argmax + H count ----------
__global__ __launch_bounds__(256) void logits_k(const float* __restrict__ X,
                                                const float* __restrict__ W,
                                                const float* __restrict__ B,
                                                float* __restrict__ H,
                                                int rows, int nN)
{
  const int lane = threadIdx.x & 63;
  const int wib  = threadIdx.x >> 6;
  const int row  = blockIdx.x * 256 + wib * 64 + lane;
  float acc[NSDIM];
#pragma unroll
  for (int c = 0; c < NSDIM; ++c) acc[c] = B[c];
  if (row >= rows) return;
  const float4* __restrict__ xr = (const float4*)(X + (size_t)row * FDIM);
#pragma unroll 2
  for (int kk = 0; kk < FDIM / 4; ++kk) {
    float4 xv = xr[kk];
    xv.x = fmaxf(xv.x, 0.f); xv.y = fmaxf(xv.y, 0.f);
    xv.z = fmaxf(xv.z, 0.f); xv.w = fmaxf(xv.w, 0.f);
    const float* __restrict__ w0 = W + (kk * 4 + 0) * NSDIM;
    const float* __restrict__ w1 = W + (kk * 4 + 1) * NSDIM;
    const float* __restrict__ w2 = W + (kk * 4 + 2) * NSDIM;
    const float* __restrict__ w3 = W + (kk * 4 + 3) * NSDIM;
#pragma unroll
    for (int c = 0; c < NSDIM; ++c) acc[c] = fmaf(xv.x, w0[c], acc[c]);
#pragma unroll
    for (int c = 0; c < NSDIM; ++c) acc[c] = fmaf(xv.y, w1[c], acc[c]);
#pragma unroll
    for (int c = 0; c < NSDIM; ++c) acc[c] = fmaf(xv.z, w2[c], acc[c]);
#pragma unroll
    for (int c = 0; c < NSDIM; ++c) acc[c] = fmaf(xv.w, w3[c], acc[c]);
  }
  float bv = acc[0]; int bi = 0;
#pragma unroll
  for (int c = 1; c < NSDIM; ++c)
    if (acc[c] > bv) { bv = acc[c]; bi = c; }   // strict > : first-index tiebreak
  int v = row;
  while (v >= nN) v -= nN;
  atomicAdd(&H[(size_t)v * NSDIM + bi], 1.f);
}

// ---------- dots = (features @ hyperT) * 0.125, tiled 4x ----------
__global__ __launch_bounds__(256) void dots_k(const float* __restrict__ X,
                                              const float* __restrict__ WT,
                                              float* __restrict__ out2, int nN)
{
  const int lane = threadIdx.x & 63;
  const int wib  = threadIdx.x >> 6;
  const int row  = blockIdx.x * 256 + wib * 64 + lane;
  if (row >= nN) return;
  float acc[NSDIM];
#pragma unroll
  for (int c = 0; c < NSDIM; ++c) acc[c] = 0.f;
  const float4* __restrict__ xr = (const float4*)(X + (size_t)row * FDIM);
#pragma unroll 2
  for (int kk = 0; kk < FDIM / 4; ++kk) {
    const float4 xv = xr[kk];
    const float* __restrict__ w0 = WT + (kk * 4 + 0) * NSDIM;
    const float* __restrict__ w1 = WT + (kk * 4 + 1) * NSDIM;
    const float* __restrict__ w2 = WT + (kk * 4 + 2) * NSDIM;
    const float* __restrict__ w3 = WT + (kk * 4 + 3) * NSDIM;
#pragma unroll
    for (int c = 0; c < NSDIM; ++c) acc[c] = fmaf(xv.x, w0[c], acc[c]);
#pragma unroll
    for (int c = 0; c < NSDIM; ++c) acc[c] = fmaf(xv.y, w1[c], acc[c]);
#pragma unroll
    for (int c = 0; c < NSDIM; ++c) acc[c] = fmaf(xv.z, w2[c], acc[c]);
#pragma unroll
    for (int c = 0; c < NSDIM; ++c) acc[c] = fmaf(xv.w, w3[c], acc[c]);
  }
#pragma unroll
  for (int c = 0; c < NSDIM; ++c) acc[c] *= 0.125f;
#pragma unroll
  for (int b = 0; b < 4; ++b) {
    float* __restrict__ orow = out2 + ((size_t)b * nN + row) * NSDIM;
#pragma unroll
    for (int c4 = 0; c4 < NSDIM / 4; ++c4)
      ((float4*)orow)[c4] = make_float4(acc[4 * c4], acc[4 * c4 + 1],
                                        acc[4 * c4 + 2], acc[4 * c4 + 3]);
  }
}

// ============================================================================
// Graph kernels
// ============================================================================

// ---------- src-CSR: counts ----------
__global__ void cntS_k(const int* __restrict__ src, int* __restrict__ cntS, int nE)
{
  for (int e = blockIdx.x * blockDim.x + threadIdx.x; e < nE;
       e += gridDim.x * blockDim.x)
    atomicAdd(&cntS[src[e]], 1);
}

// ---------- src-CSR: fill (slots hold dst; mask bits added later) ----------
__global__ void fillS_k(const int* __restrict__ src, const int* __restrict__ dst,
                        int* __restrict__ cursorS, unsigned* __restrict__ slotsS, int nE)
{
  for (int e = blockIdx.x * blockDim.x + threadIdx.x; e < nE;
       e += gridDim.x * blockDim.x) {
    int pos = atomicAdd(&cursorS[src[e]], 1);
    slotsS[pos] = (unsigned)dst[e];
  }
}

// ============================================================================
// Hierarchical parallel exclusive scan (3 phases, all fully parallel)
// ============================================================================

// phase A: per-256-tile exclusive scan (tile-local) + tile sums
__global__ __launch_bounds__(256) void scanA_k(const int* __restrict__ cnt,
                                               int* __restrict__ rowoff,
                                               int* __restrict__ tilesum, int nN)
{
  __shared__ int s[256];
  const int i = blockIdx.x * 256 + threadIdx.x;
  const int v = (i < nN) ? cnt[i] : 0;
  s[threadIdx.x] = v;
  __syncthreads();
#pragma unroll
  for (int o = 1; o < 256; o <<= 1) {
    const int t = (threadIdx.x >= o) ? s[threadIdx.x - o] : 0;
    __syncthreads();
    s[threadIdx.x] += t;
    __syncthreads();
  }
  if (i < nN) rowoff[i] = s[threadIdx.x] - v;   // tile-local exclusive
  if (threadIdx.x == 255) tilesum[blockIdx.x] = s[255];
}

// phase B: single-block exclusive scan of tile sums; tileoff[ntiles] = total
__global__ __launch_bounds__(256) void scanB_k(const int* __restrict__ tilesum,
                                               int* __restrict__ tileoff, int ntiles)
{
  __shared__ int s[256];
  __shared__ int carry;
  if (threadIdx.x == 0) carry = 0;
  __syncthreads();
  for (int base = 0; base < ntiles; base += 256) {
    const int idx = base + threadIdx.x;
    const int v = (idx < ntiles) ? tilesum[idx] : 0;
    s[threadIdx.x] = v;
    __syncthreads();
#pragma unroll
    for (int o = 1; o < 256; o <<= 1) {
      const int t = (threadIdx.x >= o) ? s[threadIdx.x - o] : 0;
      __syncthreads();
      s[threadIdx.x] += t;
      __syncthreads();
    }
    if (idx < ntiles) tileoff[idx] = carry + s[threadIdx.x] - v;
    __syncthreads();
    if (threadIdx.x == 0) carry += s[255];
    __syncthreads();
  }
  if (threadIdx.x == 0) tileoff[ntiles] = carry;
}

// phase C: add tile offsets; write cursor copy; rowoff[nN] = total
__global__ __launch_bounds__(256) void scanC_k(int* __restrict__ rowoff,
                                               int* __restrict__ cursor,
                                               const int* __restrict__ tileoff,
                                               int nN, int ntiles)
{
  const int i = blockIdx.x * 256 + threadIdx.x;
  if (i < nN) {
    const int v = rowoff[i] + tileoff[i >> 8];
    rowoff[i] = v;
    cursor[i] = v;
  }
  if (i == 0) rowoff[nN] = tileoff[ntiles];
}

// ---------- mask + degree counts: wave = 4 edges of one source, 16 lanes each ----------
__global__ void mask_cnt_k(const int* __restrict__ rowoffS, unsigned* __restrict__ slotsS,
                           const float* __restrict__ G, const float* __restrict__ f,
                           int* __restrict__ cnt, int nN)
{
  const int lane = threadIdx.x & 63;
  const int wib  = threadIdx.x >> 6;
  const int wpb  = blockDim.x >> 6;
  const int i = lane & 15;   // component quad index
  const int g = lane >> 4;   // edge sub-slot within wave
  const float4* __restrict__ G4 = (const float4*)G;
  const float4* __restrict__ f4 = (const float4*)f;
  for (int s = blockIdx.x * wpb + wib; s < nN; s += gridDim.x * wpb) {
    const int start = rowoffS[s], end = rowoffS[s + 1];
    if (start == end) continue;
    const float4 g0 = G4[((size_t)0 * nN + s) * 16 + i];
    const float4 g1 = G4[((size_t)1 * nN + s) * 16 + i];
    const float4 g2 = G4[((size_t)2 * nN + s) * 16 + i];
    for (int base = start; base < end; base += 4) {
      const int e = base + g;
      const bool valid = e < end;
      const int ee = valid ? e : start;
      const unsigned d = slotsS[ee] & 0xFFFFFu;
      const float4 fv = f4[(size_t)d * 16 + i];
      float p0 = fmaf(fv.x, g0.x, fmaf(fv.y, g0.y, fmaf(fv.z, g0.z, fv.w * g0.w)));
      float p1 = fmaf(fv.x, g1.x, fmaf(fv.y, g1.y, fmaf(fv.z, g1.z, fv.w * g1.w)));
      float p2 = fmaf(fv.x, g2.x, fmaf(fv.y, g2.y, fmaf(fv.z, g2.z, fv.w * g2.w)));
#pragma unroll
      for (int o = 8; o > 0; o >>= 1) {
        p0 += __shfl_xor(p0, o);
        p1 += __shfl_xor(p1, o);
        p2 += __shfl_xor(p2, o);
      }
      if (i == 0 && valid) {
        unsigned m = (p0 > 0.f ? 1u : 0u) | (p1 > 0.f ? 2u : 0u) | (p2 > 0.f ? 4u : 0u);
        if (m) slotsS[e] = d | (m << 20);
        atomicAdd(&cnt[d], 1);
        if (m & 1u) atomicAdd(&cnt[nN + d], 1);
        if (m & 2u) atomicAdd(&cnt[2 * nN + d], 1);
        if (m & 4u) atomicAdd(&cnt[3 * nN + d], 1);
      }
    }
  }
}

// ---------- dst-CSR fill from src-CSR slots (wave per source, lane per slot) ----------
__global__ void fillD_k(const int* __restrict__ rowoffS, const unsigned* __restrict__ slotsS,
                        int* __restrict__ cursorD, unsigned* __restrict__ csrD, int nN)
{
  const int lane = threadIdx.x & 63;
  const int wib  = threadIdx.x >> 6;
  const int wpb  = blockDim.x >> 6;
  for (int s = blockIdx.x * wpb + wib; s < nN; s += gridDim.x * wpb) {
    const int start = rowoffS[s], end = rowoffS[s + 1];
    for (int pos = start + lane; pos < end; pos += 64) {
      const unsigned v = slotsS[pos];
      const unsigned d = v & 0xFFFFFu;
      const unsigned m = v >> 20;
      int p = atomicAdd(&cursorD[d], 1);
      csrD[p] = (unsigned)s | (m << 20);
    }
  }
}

// ---------- dinv from int counts ----------
__global__ void dinv_k(const int* __restrict__ cnt, float* __restrict__ dinv, int nN)
{
  int i = blockIdx.x * blockDim.x + threadIdx.x;
  int tot = 4 * nN;
  if (i < tot) {
    float base = (i < nN) ? 1.f : 2.f;  // block0: +self ; replicas: +identity edge +self
    dinv[i] = 1.f / sqrtf((float)cnt[i] + base);
  }
}

// ---------- fused CSR gather + GCN finish (wave per destination node) ----------
template<bool L0, bool RELU>
__global__ void gather_finish_k(const int* __restrict__ rowoff, const unsigned* __restrict__ csr,
                                const float* __restrict__ xws, const float* __restrict__ xw,
                                const float* __restrict__ dinv, const float* __restrict__ bias,
                                float* __restrict__ out, int nN)
{
  const int lane = threadIdx.x & 63;
  const int wib  = threadIdx.x >> 6;
  const int wpb  = blockDim.x >> 6;
  const float b = bias[lane];
  for (int d = blockIdx.x * wpb + wib; d < nN; d += gridDim.x * wpb) {
    const int start = rowoff[d], end = rowoff[d + 1];
    float a0 = 0.f, a1 = 0.f, a2 = 0.f, a3 = 0.f;
    for (int base = start; base < end; base += 64) {
      const int nrem = end - base;
      unsigned p = (lane < nrem) ? csr[base + lane] : 0u;
      const int cntj = nrem < 64 ? nrem : 64;
      for (int j = 0; j < cntj; ++j) {
        const unsigned pj = (unsigned)__shfl((int)p, j);
        const int s = (int)(pj & 0xFFFFFu);
        const unsigned mk = pj >> 20;
        const float v = xws[(size_t)s * FDIM + lane];
        a0 += v;
        if (mk & 1u) a1 += v;
        if (mk & 2u) a2 += v;
        if (mk & 4u) a3 += v;
      }
    }
    const float di0 = dinv[d];
    const float xs  = xws[(size_t)d * FDIM + lane];
    const float xb0 = xw[(size_t)d * FDIM + lane];

    float r0 = (a0 + xs) * di0 + b;
    if (RELU) r0 = fmaxf(r0, 0.f);
    out[(size_t)d * FDIM + lane] = r0;

#pragma unroll
    for (int t = 1; t <= 3; ++t) {
      const float at = (t == 1) ? a1 : (t == 2) ? a2 : a3;
      const float dit = dinv[t * nN + d];
      const float self = L0 ? xb0 : xw[((size_t)t * nN + d) * FDIM + lane];
      float r = (at + xs + self * dit) * dit + b;
      if (RELU) r = fmaxf(r, 0.f);
      out[((size_t)t * nN + d) * FDIM + lane] = r;
    }
  }
}

// ---------- hyper[j,:] += x2_b0[i,:] where H[i,j] > 0 (LDS-accumulated) ----------
__global__ void hyper_k(const float* __restrict__ H, const float* __restrict__ x2,
                        float* __restrict__ hyper, int nN)
{
  __shared__ float hl[NSDIM * FDIM];
  for (int i = threadIdx.x; i < NSDIM * FDIM; i += blockDim.x) hl[i] = 0.f;
  __syncthreads();
  const int lane = threadIdx.x & 63;
  const int wib  = threadIdx.x >> 6;
  const int wpb  = blockDim.x >> 6;
  for (int i = blockIdx.x * wpb + wib; i < nN; i += gridDim.x * wpb) {
    float hv = H[(size_t)i * NSDIM + lane];
    unsigned long long ball = __ballot(hv > 0.f);
    float x = x2[(size_t)i * FDIM + lane];
    while (ball) {
      int j = __ffsll((unsigned long long)ball) - 1;
      ball &= ball - 1;
      atomicAdd(&hl[j * FDIM + lane], x);
    }
  }
  __syncthreads();
  for (int i = threadIdx.x; i < NSDIM * FDIM; i += blockDim.x) {
    float v = hl[i];
    if (v != 0.f) atomicAdd(&hyper[i], v);
  }
}

// ---------- hyper -> out1 + transposed copy for dots ----------
__global__ void hfin_k(const float* __restrict__ hyper, float* __restrict__ out1,
                       float* __restrict__ hyperT)
{
  int idx = blockIdx.x * blockDim.x + threadIdx.x;
  if (idx < NSDIM * FDIM) {
    float v = hyper[idx];
    out1[idx] = v;
    int j = idx >> 6, k = idx & 63;
    hyperT[k * NSDIM + j] = v;
  }
}

// ---------- per-column histogram -> max + softmax denominator (H in {0..4}) ----------
__global__ void colstats_k(const float* __restrict__ H, float* __restrict__ cmax,
                           float* __restrict__ cden, int nN)
{
  __shared__ int s[8];
  const int j = blockIdx.x;
  if (threadIdx.x < 8) s[threadIdx.x] = 0;
  __syncthreads();
  int c[5] = {0, 0, 0, 0, 0};
  for (int i = threadIdx.x; i < nN; i += blockDim.x) {
    int v = (int)H[(size_t)i * NSDIM + j];
    c[v]++;
  }
#pragma unroll
  for (int k = 0; k < 5; ++k) atomicAdd(&s[k], c[k]);
  __syncthreads();
  if (threadIdx.x == 0) {
    int m = 0;
#pragma unroll
    for (int k = 0; k < 5; ++k) if (s[k] > 0) m = k;
    float den = 0.f;
#pragma unroll
    for (int k = 0; k < 5; ++k) den += (float)s[k] * expf((float)(k - m));
    cmax[j] = (float)m;
    cden[j] = den;
  }
}

__global__ void hsoft_k(const float* __restrict__ H, const float* __restrict__ cmax,
                        const float* __restrict__ cden, float* __restrict__ out0, int nN)
{
  int idx = blockIdx.x * blockDim.x + threadIdx.x;
  int tot = nN * NSDIM;
  if (idx < tot) {
    int j = idx & (NSDIM - 1);
    out0[idx] = expf(H[idx] - cmax[j]) / cden[j];
  }
}

// ---------- host ----------
extern "C" void kernel_launch(void* const* d_in, const int* in_sizes, int n_in,
                              void* d_out, int out_size, void* d_ws, size_t ws_size,
                              hipStream_t stream)
{
  const int* edge_index = (const int*)d_in[0];
  const float* features = (const float*)d_in[1];
  const float* W_lin    = (const float*)d_in[2];
  const float* b_lin    = (const float*)d_in[3];
  const float* gcn0_W   = (const float*)d_in[4];
  const float* gcn0_b   = (const float*)d_in[5];
  const float* gcn1_W   = (const float*)d_in[6];
  const float* gcn1_b   = (const float*)d_in[7];
  const float* lin1_W   = (const float*)d_in[8];
  const float* lin1_b   = (const float*)d_in[9];

  const int E = in_sizes[0] / 2;
  const int N = in_sizes[1] / FDIM;

  const int* src = edge_index;
  const int* dst = edge_index + E;

  // workspace layout
  float* ws    = (float*)d_ws;
  float* G     = ws;                                   // 3*N*F (dead after mask_cnt)
  int*   cnt   = (int*)(G + (size_t)TREP * N * FDIM);  // 4N
  float* dinv  = (float*)(cnt + (size_t)4 * N);        // 4N
  int*   cntS  = (int*)(dinv + (size_t)4 * N);         // N (also cursorS)
  int*   rowoffS = cntS + N;                           // N+64
  unsigned* slotsS = (unsigned*)(rowoffS + N + 64);    // E
  float* xw0   = (float*)(slotsS + E);                 // N*F
  float* bufA  = xw0 + (size_t)N * FDIM;               // 4N*F (x1 -> x2)
  float* bufB  = bufA + (size_t)4 * N * FDIM;          // 4N*F (xw1)
  float* Harr  = bufB + (size_t)4 * N * FDIM;          // N*NS
  float* hyper = Harr + (size_t)N * NSDIM;             // NS*F
  float* cmax  = hyper + NSDIM * FDIM;                 // NS
  float* cden  = cmax + NSDIM;                         // NS
  float* hyperT = cden + NSDIM;                        // NS*F
  int*   tilesum = (int*)(hyperT + NSDIM * FDIM);      // ntiles+1
  int*   tileoff = tilesum + ((N + 255) / 256 + 1);    // ntiles+1

  // dst-CSR + scaled message table alias the (dead-after-mask) G region
  int* rowoffD     = (int*)G;                          // N+64
  int* cursorD     = rowoffD + (N + 64);               // N
  unsigned* csrD   = (unsigned*)(cursorD + N);         // E
  float* xws       = (float*)(csrD + E);               // N*F

  float* out0 = (float*)d_out;             // H_soft (N,NS)
  float* out1 = out0 + (size_t)N * NSDIM;  // hyper (NS,F)
  float* out2 = out1 + NSDIM * FDIM;       // dots (4N,NS)

  const int BLK = 256;
  const int WPB = BLK / 64;
  const int ntiles = (N + 255) / 256;
  auto wgrid = [](int items, int wpb) { return (items + wpb - 1) / wpb; };
  auto tgrid = [](int rows) { return (rows + 255) / 256; };

  // zero accumulators
  hipMemsetAsync(cnt, 0, (size_t)4 * N * sizeof(int), stream);
  hipMemsetAsync(cntS, 0, (size_t)N * sizeof(int), stream);
  hipMemsetAsync(Harr, 0, (size_t)N * NSDIM * sizeof(float), stream);
  hipMemsetAsync(hyper, 0, (size_t)NSDIM * FDIM * sizeof(float), stream);

  // 1) src-CSR build: counts -> parallel scan -> fill
  cntS_k<<<1024, BLK, 0, stream>>>(src, cntS, E);
  scanA_k<<<ntiles, 256, 0, stream>>>(cntS, rowoffS, tilesum, N);
  scanB_k<<<1, 256, 0, stream>>>(tilesum, tileoff, ntiles);
  scanC_k<<<ntiles, 256, 0, stream>>>(rowoffS, cntS, tileoff, N, ntiles); // cntS -> cursorS
  fillS_k<<<1024, BLK, 0, stream>>>(src, dst, cntS, slotsS, E);

  // 2) G = normf*trans - normt*f  (trans/norms never materialized)
  {
    dim3 g(tgrid(N), TREP);
    gmat_k<<<g, BLK, 0, stream>>>(features, W_lin, b_lin, G, N);
  }

  // 3) mask + degree counts (4 edges/wave, 16-lane groups)
  mask_cnt_k<<<wgrid(N, WPB), BLK, 0, stream>>>(rowoffS, slotsS, G, features, cnt, N);

  // 4) dst-CSR build (G dead; rowoffD/cursorD/csrD/xws alias it)
  scanA_k<<<ntiles, 256, 0, stream>>>(cnt, rowoffD, tilesum, N);
  scanB_k<<<1, 256, 0, stream>>>(tilesum, tileoff, ntiles);
  scanC_k<<<ntiles, 256, 0, stream>>>(rowoffD, cursorD, tileoff, N, ntiles);
  fillD_k<<<wgrid(N, WPB), BLK, 0, stream>>>(rowoffS, slotsS, cursorD, csrD, N);

  // 5) dinv
  dinv_k<<<(4 * N + BLK - 1) / BLK, BLK, 0, stream>>>(cnt, dinv, N);

  // 6) xw0 = relu(features) @ gcn0_W ; fused xws = xw0 * dinv0
  gemm_k<true><<<tgrid(N), BLK, 0, stream>>>(features, gcn0_W, xw0, N, xws, dinv, N);

  // 7) gcn0 gather+finish -> x1 (relu'd) in bufA
  gather_finish_k<true, true><<<wgrid(N, WPB), BLK, 0, stream>>>(
      rowoffD, csrD, xws, xw0, dinv, gcn0_b, bufA, N);

  // 8) xw1 = x1 @ gcn1_W (4N rows); fused xws = xw1(block0) * dinv0
  gemm_k<false><<<tgrid(4 * N), BLK, 0, stream>>>(bufA, gcn1_W, bufB, 4 * N, xws, dinv, N);

  // 9) gcn1 gather+finish -> x2 in bufA (no relu)
  gather_finish_k<false, false><<<wgrid(N, WPB), BLK, 0, stream>>>(
      rowoffD, csrD, xws, bufB, dinv, gcn1_b, bufA, N);

  // 10) logits + argmax -> H counts
  logits_k<<<tgrid(4 * N), BLK, 0, stream>>>(bufA, lin1_W, lin1_b, Harr, 4 * N, N);

  // 11) hyper (LDS-accumulated) + out1 + transpose
  hyper_k<<<128, BLK, 0, stream>>>(Harr, bufA, hyper, N);
  hfin_k<<<(NSDIM * FDIM + BLK - 1) / BLK, BLK, 0, stream>>>(hyper, out1, hyperT);

  // 12) H softmax over axis 0
  colstats_k<<<NSDIM, BLK, 0, stream>>>(Harr, cmax, cden, N);
  hsoft_k<<<(N * NSDIM + BLK - 1) / BLK, BLK, 0, stream>>>(Harr, cmax, cden, out0, N);

  // 13) dots
  dots_k<<<tgrid(N), BLK, 0, stream>>>(features, hyperT, out2, N);
}

// Round 7
// 658.486 us; speedup vs baseline: 1.4801x; 1.1436x over previous
//
#include <hip/hip_runtime.h>

#define FDIM 64
#define NSDIM 64
#define TREP 3
#define EPSV 1e-8f

// ============================================================================
// Register-tile GEMM family: one lane owns one output row (64 f32 accumulators
// in VGPRs). X row loaded per-lane as float4 (VMEM); W rows read via wave-
// uniform pointers -> scalar loads (SGPR). No LDS-pipe traffic.
// ============================================================================

// ---------- G matrix: G[t,r,:] = normf(r)*(X[r]@W[t]+b[t]) - |X[r]@W[t]+b[t]|*X[r] ----------
__global__ __launch_bounds__(256) void gmat_k(const float* __restrict__ X,
                                              const float* __restrict__ W,
                                              const float* __restrict__ B,
                                              float* __restrict__ G, int nN)
{
  const int t    = blockIdx.y;
  const int lane = threadIdx.x & 63;
  const int wib  = threadIdx.x >> 6;
  const int row  = blockIdx.x * 256 + wib * 64 + lane;
  const float* __restrict__ Wt = W + (size_t)t * FDIM * FDIM;
  const float* __restrict__ Bt = B + t * FDIM;
  float acc[FDIM];
#pragma unroll
  for (int c = 0; c < FDIM; ++c) acc[c] = Bt[c];
  if (row >= nN) return;
  const float4* __restrict__ xr = (const float4*)(X + (size_t)row * FDIM);
  float ss = 0.f;
#pragma unroll 2
  for (int kk = 0; kk < FDIM / 4; ++kk) {
    const float4 xv = xr[kk];
    ss = fmaf(xv.x, xv.x, fmaf(xv.y, xv.y, fmaf(xv.z, xv.z, fmaf(xv.w, xv.w, ss))));
    const float* __restrict__ w0 = Wt + (kk * 4 + 0) * FDIM;
    const float* __restrict__ w1 = Wt + (kk * 4 + 1) * FDIM;
    const float* __restrict__ w2 = Wt + (kk * 4 + 2) * FDIM;
    const float* __restrict__ w3 = Wt + (kk * 4 + 3) * FDIM;
#pragma unroll
    for (int c = 0; c < FDIM; ++c) acc[c] = fmaf(xv.x, w0[c], acc[c]);
#pragma unroll
    for (int c = 0; c < FDIM; ++c) acc[c] = fmaf(xv.y, w1[c], acc[c]);
#pragma unroll
    for (int c = 0; c < FDIM; ++c) acc[c] = fmaf(xv.z, w2[c], acc[c]);
#pragma unroll
    for (int c = 0; c < FDIM; ++c) acc[c] = fmaf(xv.w, w3[c], acc[c]);
  }
  float sq = 0.f;
#pragma unroll
  for (int c = 0; c < FDIM; ++c) sq = fmaf(acc[c], acc[c], sq);
  const float nf = fmaxf(sqrtf(ss), EPSV);
  const float na = fmaxf(sqrtf(sq), EPSV);
  float* __restrict__ grow = G + ((size_t)t * nN + row) * FDIM;
#pragma unroll
  for (int c4 = 0; c4 < FDIM / 4; ++c4) {
    const float4 xv = xr[c4];
    ((float4*)grow)[c4] = make_float4(
        fmaf(nf, acc[4 * c4 + 0], -na * xv.x),
        fmaf(nf, acc[4 * c4 + 1], -na * xv.y),
        fmaf(nf, acc[4 * c4 + 2], -na * xv.z),
        fmaf(nf, acc[4 * c4 + 3], -na * xv.w));
  }
}

// ---------- generic: out[r,:] = act(X[r,:]) @ W ; fused scaled copy ----------
template<bool RELU_IN>
__global__ __launch_bounds__(256) void gemm_k(const float* __restrict__ X,
                                              const float* __restrict__ W,
                                              float* __restrict__ out, int rows,
                                              float* __restrict__ scaled,
                                              const float* __restrict__ dinv, int nScaled)
{
  const int lane = threadIdx.x & 63;
  const int wib  = threadIdx.x >> 6;
  const int row  = blockIdx.x * 256 + wib * 64 + lane;
  if (row >= rows) return;
  float acc[FDIM];
#pragma unroll
  for (int c = 0; c < FDIM; ++c) acc[c] = 0.f;
  const float4* __restrict__ xr = (const float4*)(X + (size_t)row * FDIM);
#pragma unroll 2
  for (int kk = 0; kk < FDIM / 4; ++kk) {
    float4 xv = xr[kk];
    if (RELU_IN) {
      xv.x = fmaxf(xv.x, 0.f); xv.y = fmaxf(xv.y, 0.f);
      xv.z = fmaxf(xv.z, 0.f); xv.w = fmaxf(xv.w, 0.f);
    }
    const float* __restrict__ w0 = W + (kk * 4 + 0) * FDIM;
    const float* __restrict__ w1 = W + (kk * 4 + 1) * FDIM;
    const float* __restrict__ w2 = W + (kk * 4 + 2) * FDIM;
    const float* __restrict__ w3 = W + (kk * 4 + 3) * FDIM;
#pragma unroll
    for (int c = 0; c < FDIM; ++c) acc[c] = fmaf(xv.x, w0[c], acc[c]);
#pragma unroll
    for (int c = 0; c < FDIM; ++c) acc[c] = fmaf(xv.y, w1[c], acc[c]);
#pragma unroll
    for (int c = 0; c < FDIM; ++c) acc[c] = fmaf(xv.z, w2[c], acc[c]);
#pragma unroll
    for (int c = 0; c < FDIM; ++c) acc[c] = fmaf(xv.w, w3[c], acc[c]);
  }
  float* __restrict__ orow = out + (size_t)row * FDIM;
#pragma unroll
  for (int c4 = 0; c4 < FDIM / 4; ++c4)
    ((float4*)orow)[c4] = make_float4(acc[4 * c4], acc[4 * c4 + 1],
                                      acc[4 * c4 + 2], acc[4 * c4 + 3]);
  if (scaled != nullptr && row < nScaled) {
    const float dv = dinv[row];
    float* __restrict__ srow = scaled + (size_t)row * FDIM;
#pragma unroll
    for (int c4 = 0; c4 < FDIM / 4; ++c4)
      ((float4*)srow)[c4] = make_float4(acc[4 * c4] * dv, acc[4 * c4 + 1] * dv,
                                        acc[4 * c4 + 2] * dv, acc[4 * c4 + 3] * dv);
  }
}

// ---------- logits + per-lane argmax + H count ----------
__global__ __launch_bounds__(256) void logits_k(const float* __restrict__ X,
                                                const float* __restrict__ W,
                                                const float* __restrict__ B,
                                                float* __restrict__ H,
                                                int rows, int nN)
{
  const int lane = threadIdx.x & 63;
  const int wib  = threadIdx.x >> 6;
  const int row  = blockIdx.x * 256 + wib * 64 + lane;
  float acc[NSDIM];
#pragma unroll
  for (int c = 0; c < NSDIM; ++c) acc[c] = B[c];
  if (row >= rows) return;
  const float4* __restrict__ xr = (const float4*)(X + (size_t)row * FDIM);
#pragma unroll 2
  for (int kk = 0; kk < FDIM / 4; ++kk) {
    float4 xv = xr[kk];
    xv.x = fmaxf(xv.x, 0.f); xv.y = fmaxf(xv.y, 0.f);
    xv.z = fmaxf(xv.z, 0.f); xv.w = fmaxf(xv.w, 0.f);
    const float* __restrict__ w0 = W + (kk * 4 + 0) * NSDIM;
    const float* __restrict__ w1 = W + (kk * 4 + 1) * NSDIM;
    const float* __restrict__ w2 = W + (kk * 4 + 2) * NSDIM;
    const float* __restrict__ w3 = W + (kk * 4 + 3) * NSDIM;
#pragma unroll
    for (int c = 0; c < NSDIM; ++c) acc[c] = fmaf(xv.x, w0[c], acc[c]);
#pragma unroll
    for (int c = 0; c < NSDIM; ++c) acc[c] = fmaf(xv.y, w1[c], acc[c]);
#pragma unroll
    for (int c = 0; c < NSDIM; ++c) acc[c] = fmaf(xv.z, w2[c], acc[c]);
#pragma unroll
    for (int c = 0; c < NSDIM; ++c) acc[c] = fmaf(xv.w, w3[c], acc[c]);
  }
  float bv = acc[0]; int bi = 0;
#pragma unroll
  for (int c = 1; c < NSDIM; ++c)
    if (acc[c] > bv) { bv = acc[c]; bi = c; }   // strict > : first-index tiebreak
  int v = row;
  while (v >= nN) v -= nN;
  atomicAdd(&H[(size_t)v * NSDIM + bi], 1.f);
}

// ---------- dots = (features @ hyperT) * 0.125, tiled 4x ----------
__global__ __launch_bounds__(256) void dots_k(const float* __restrict__ X,
                                              const float* __restrict__ WT,
                                              float* __restrict__ out2, int nN)
{
  const int lane = threadIdx.x & 63;
  const int wib  = threadIdx.x >> 6;
  const int row  = blockIdx.x * 256 + wib * 64 + lane;
  if (row >= nN) return;
  float acc[NSDIM];
#pragma unroll
  for (int c = 0; c < NSDIM; ++c) acc[c] = 0.f;
  const float4* __restrict__ xr = (const float4*)(X + (size_t)row * FDIM);
#pragma unroll 2
  for (int kk = 0; kk < FDIM / 4; ++kk) {
    const float4 xv = xr[kk];
    const float* __restrict__ w0 = WT + (kk * 4 + 0) * NSDIM;
    const float* __restrict__ w1 = WT + (kk * 4 + 1) * NSDIM;
    const float* __restrict__ w2 = WT + (kk * 4 + 2) * NSDIM;
    const float* __restrict__ w3 = WT + (kk * 4 + 3) * NSDIM;
#pragma unroll
    for (int c = 0; c < NSDIM; ++c) acc[c] = fmaf(xv.x, w0[c], acc[c]);
#pragma unroll
    for (int c = 0; c < NSDIM; ++c) acc[c] = fmaf(xv.y, w1[c], acc[c]);
#pragma unroll
    for (int c = 0; c < NSDIM; ++c) acc[c] = fmaf(xv.z, w2[c], acc[c]);
#pragma unroll
    for (int c = 0; c < NSDIM; ++c) acc[c] = fmaf(xv.w, w3[c], acc[c]);
  }
#pragma unroll
  for (int c = 0; c < NSDIM; ++c) acc[c] *= 0.125f;
#pragma unroll
  for (int b = 0; b < 4; ++b) {
    float* __restrict__ orow = out2 + ((size_t)b * nN + row) * NSDIM;
#pragma unroll
    for (int c4 = 0; c4 < NSDIM / 4; ++c4)
      ((float4*)orow)[c4] = make_float4(acc[4 * c4], acc[4 * c4 + 1],
                                        acc[4 * c4 + 2], acc[4 * c4 + 3]);
  }
}

// ============================================================================
// Graph kernels
// ============================================================================

// ---------- src-CSR: counts ----------
__global__ void cntS_k(const int* __restrict__ src, int* __restrict__ cntS, int nE)
{
  for (int e = blockIdx.x * blockDim.x + threadIdx.x; e < nE;
       e += gridDim.x * blockDim.x)
    atomicAdd(&cntS[src[e]], 1);
}

// ---------- src-CSR: fill (slots hold dst; mask bits added later) ----------
__global__ void fillS_k(const int* __restrict__ src, const int* __restrict__ dst,
                        int* __restrict__ cursorS, unsigned* __restrict__ slotsS, int nE)
{
  for (int e = blockIdx.x * blockDim.x + threadIdx.x; e < nE;
       e += gridDim.x * blockDim.x) {
    int pos = atomicAdd(&cursorS[src[e]], 1);
    slotsS[pos] = (unsigned)dst[e];
  }
}

// ============================================================================
// Hierarchical parallel exclusive scan (3 phases, all fully parallel)
// ============================================================================

__global__ __launch_bounds__(256) void scanA_k(const int* __restrict__ cnt,
                                               int* __restrict__ rowoff,
                                               int* __restrict__ tilesum, int nN)
{
  __shared__ int s[256];
  const int i = blockIdx.x * 256 + threadIdx.x;
  const int v = (i < nN) ? cnt[i] : 0;
  s[threadIdx.x] = v;
  __syncthreads();
#pragma unroll
  for (int o = 1; o < 256; o <<= 1) {
    const int t = (threadIdx.x >= o) ? s[threadIdx.x - o] : 0;
    __syncthreads();
    s[threadIdx.x] += t;
    __syncthreads();
  }
  if (i < nN) rowoff[i] = s[threadIdx.x] - v;   // tile-local exclusive
  if (threadIdx.x == 255) tilesum[blockIdx.x] = s[255];
}

__global__ __launch_bounds__(256) void scanB_k(const int* __restrict__ tilesum,
                                               int* __restrict__ tileoff, int ntiles)
{
  __shared__ int s[256];
  __shared__ int carry;
  if (threadIdx.x == 0) carry = 0;
  __syncthreads();
  for (int base = 0; base < ntiles; base += 256) {
    const int idx = base + threadIdx.x;
    const int v = (idx < ntiles) ? tilesum[idx] : 0;
    s[threadIdx.x] = v;
    __syncthreads();
#pragma unroll
    for (int o = 1; o < 256; o <<= 1) {
      const int t = (threadIdx.x >= o) ? s[threadIdx.x - o] : 0;
      __syncthreads();
      s[threadIdx.x] += t;
      __syncthreads();
    }
    if (idx < ntiles) tileoff[idx] = carry + s[threadIdx.x] - v;
    __syncthreads();
    if (threadIdx.x == 0) carry += s[255];
    __syncthreads();
  }
  if (threadIdx.x == 0) tileoff[ntiles] = carry;
}

__global__ __launch_bounds__(256) void scanC_k(int* __restrict__ rowoff,
                                               int* __restrict__ cursor,
                                               const int* __restrict__ tileoff,
                                               int nN, int ntiles)
{
  const int i = blockIdx.x * 256 + threadIdx.x;
  if (i < nN) {
    const int v = rowoff[i] + tileoff[i >> 8];
    rowoff[i] = v;
    cursor[i] = v;
  }
  if (i == 0) rowoff[nN] = tileoff[ntiles];
}

// ---------- mask + degree counts ----------
// wave = one source; 4 groups x 16 lanes; MAIN LOOP: 16 edges/iter (4/group),
// 4 independent f4 gathers in flight per group for MLP.
__global__ void mask_cnt_k(const int* __restrict__ rowoffS, unsigned* __restrict__ slotsS,
                           const float* __restrict__ G, const float* __restrict__ f,
                           int* __restrict__ cnt, int nN)
{
  const int lane = threadIdx.x & 63;
  const int wib  = threadIdx.x >> 6;
  const int wpb  = blockDim.x >> 6;
  const int i = lane & 15;   // component quad index
  const int g = lane >> 4;   // group within wave
  const float4* __restrict__ G4 = (const float4*)G;
  const float4* __restrict__ f4 = (const float4*)f;
  for (int s = blockIdx.x * wpb + wib; s < nN; s += gridDim.x * wpb) {
    const int start = rowoffS[s], end = rowoffS[s + 1];
    if (start == end) continue;
    const float4 g0 = G4[((size_t)0 * nN + s) * 16 + i];
    const float4 g1 = G4[((size_t)1 * nN + s) * 16 + i];
    const float4 g2 = G4[((size_t)2 * nN + s) * 16 + i];
    int base = start;
    // main: 16 edges per wave-iteration, group g owns edges base+4g..base+4g+3
    for (; base + 16 <= end; base += 16) {
      const int e = base + g * 4;
      const unsigned w0 = slotsS[e + 0] & 0xFFFFFu;
      const unsigned w1 = slotsS[e + 1] & 0xFFFFFu;
      const unsigned w2 = slotsS[e + 2] & 0xFFFFFu;
      const unsigned w3 = slotsS[e + 3] & 0xFFFFFu;
      const float4 fv0 = f4[(size_t)w0 * 16 + i];
      const float4 fv1 = f4[(size_t)w1 * 16 + i];
      const float4 fv2 = f4[(size_t)w2 * 16 + i];
      const float4 fv3 = f4[(size_t)w3 * 16 + i];
      float p00 = fmaf(fv0.x, g0.x, fmaf(fv0.y, g0.y, fmaf(fv0.z, g0.z, fv0.w * g0.w)));
      float p01 = fmaf(fv0.x, g1.x, fmaf(fv0.y, g1.y, fmaf(fv0.z, g1.z, fv0.w * g1.w)));
      float p02 = fmaf(fv0.x, g2.x, fmaf(fv0.y, g2.y, fmaf(fv0.z, g2.z, fv0.w * g2.w)));
      float p10 = fmaf(fv1.x, g0.x, fmaf(fv1.y, g0.y, fmaf(fv1.z, g0.z, fv1.w * g0.w)));
      float p11 = fmaf(fv1.x, g1.x, fmaf(fv1.y, g1.y, fmaf(fv1.z, g1.z, fv1.w * g1.w)));
      float p12 = fmaf(fv1.x, g2.x, fmaf(fv1.y, g2.y, fmaf(fv1.z, g2.z, fv1.w * g2.w)));
      float p20 = fmaf(fv2.x, g0.x, fmaf(fv2.y, g0.y, fmaf(fv2.z, g0.z, fv2.w * g0.w)));
      float p21 = fmaf(fv2.x, g1.x, fmaf(fv2.y, g1.y, fmaf(fv2.z, g1.z, fv2.w * g1.w)));
      float p22 = fmaf(fv2.x, g2.x, fmaf(fv2.y, g2.y, fmaf(fv2.z, g2.z, fv2.w * g2.w)));
      float p30 = fmaf(fv3.x, g0.x, fmaf(fv3.y, g0.y, fmaf(fv3.z, g0.z, fv3.w * g0.w)));
      float p31 = fmaf(fv3.x, g1.x, fmaf(fv3.y, g1.y, fmaf(fv3.z, g1.z, fv3.w * g1.w)));
      float p32 = fmaf(fv3.x, g2.x, fmaf(fv3.y, g2.y, fmaf(fv3.z, g2.z, fv3.w * g2.w)));
#pragma unroll
      for (int o = 8; o > 0; o >>= 1) {
        p00 += __shfl_xor(p00, o); p01 += __shfl_xor(p01, o); p02 += __shfl_xor(p02, o);
        p10 += __shfl_xor(p10, o); p11 += __shfl_xor(p11, o); p12 += __shfl_xor(p12, o);
        p20 += __shfl_xor(p20, o); p21 += __shfl_xor(p21, o); p22 += __shfl_xor(p22, o);
        p30 += __shfl_xor(p30, o); p31 += __shfl_xor(p31, o); p32 += __shfl_xor(p32, o);
      }
      if (i == 0) {
        const unsigned m0 = (p00 > 0.f ? 1u : 0u) | (p01 > 0.f ? 2u : 0u) | (p02 > 0.f ? 4u : 0u);
        const unsigned m1 = (p10 > 0.f ? 1u : 0u) | (p11 > 0.f ? 2u : 0u) | (p12 > 0.f ? 4u : 0u);
        const unsigned m2 = (p20 > 0.f ? 1u : 0u) | (p21 > 0.f ? 2u : 0u) | (p22 > 0.f ? 4u : 0u);
        const unsigned m3 = (p30 > 0.f ? 1u : 0u) | (p31 > 0.f ? 2u : 0u) | (p32 > 0.f ? 4u : 0u);
        if (m0) slotsS[e + 0] = w0 | (m0 << 20);
        if (m1) slotsS[e + 1] = w1 | (m1 << 20);
        if (m2) slotsS[e + 2] = w2 | (m2 << 20);
        if (m3) slotsS[e + 3] = w3 | (m3 << 20);
        atomicAdd(&cnt[w0], 1);
        if (m0 & 1u) atomicAdd(&cnt[nN + w0], 1);
        if (m0 & 2u) atomicAdd(&cnt[2 * nN + w0], 1);
        if (m0 & 4u) atomicAdd(&cnt[3 * nN + w0], 1);
        atomicAdd(&cnt[w1], 1);
        if (m1 & 1u) atomicAdd(&cnt[nN + w1], 1);
        if (m1 & 2u) atomicAdd(&cnt[2 * nN + w1], 1);
        if (m1 & 4u) atomicAdd(&cnt[3 * nN + w1], 1);
        atomicAdd(&cnt[w2], 1);
        if (m2 & 1u) atomicAdd(&cnt[nN + w2], 1);
        if (m2 & 2u) atomicAdd(&cnt[2 * nN + w2], 1);
        if (m2 & 4u) atomicAdd(&cnt[3 * nN + w2], 1);
        atomicAdd(&cnt[w3], 1);
        if (m3 & 1u) atomicAdd(&cnt[nN + w3], 1);
        if (m3 & 2u) atomicAdd(&cnt[2 * nN + w3], 1);
        if (m3 & 4u) atomicAdd(&cnt[3 * nN + w3], 1);
      }
    }
    // tail: 4 edges per iteration (group g owns edge base+g)
    for (; base < end; base += 4) {
      const int e = base + g;
      const bool valid = e < end;
      const int ee = valid ? e : start;
      const unsigned d = slotsS[ee] & 0xFFFFFu;
      const float4 fv = f4[(size_t)d * 16 + i];
      float p0 = fmaf(fv.x, g0.x, fmaf(fv.y, g0.y, fmaf(fv.z, g0.z, fv.w * g0.w)));
      float p1 = fmaf(fv.x, g1.x, fmaf(fv.y, g1.y, fmaf(fv.z, g1.z, fv.w * g1.w)));
      float p2 = fmaf(fv.x, g2.x, fmaf(fv.y, g2.y, fmaf(fv.z, g2.z, fv.w * g2.w)));
#pragma unroll
      for (int o = 8; o > 0; o >>= 1) {
        p0 += __shfl_xor(p0, o);
        p1 += __shfl_xor(p1, o);
        p2 += __shfl_xor(p2, o);
      }
      if (i == 0 && valid) {
        unsigned m = (p0 > 0.f ? 1u : 0u) | (p1 > 0.f ? 2u : 0u) | (p2 > 0.f ? 4u : 0u);
        if (m) slotsS[e] = d | (m << 20);
        atomicAdd(&cnt[d], 1);
        if (m & 1u) atomicAdd(&cnt[nN + d], 1);
        if (m & 2u) atomicAdd(&cnt[2 * nN + d], 1);
        if (m & 4u) atomicAdd(&cnt[3 * nN + d], 1);
      }
    }
  }
}

// ---------- dst-CSR fill from src-CSR slots (wave per source, lane per slot) ----------
__global__ void fillD_k(const int* __restrict__ rowoffS, const unsigned* __restrict__ slotsS,
                        int* __restrict__ cursorD, unsigned* __restrict__ csrD, int nN)
{
  const int lane = threadIdx.x & 63;
  const int wib  = threadIdx.x >> 6;
  const int wpb  = blockDim.x >> 6;
  for (int s = blockIdx.x * wpb + wib; s < nN; s += gridDim.x * wpb) {
    const int start = rowoffS[s], end = rowoffS[s + 1];
    for (int pos = start + lane; pos < end; pos += 64) {
      const unsigned v = slotsS[pos];
      const unsigned d = v & 0xFFFFFu;
      const unsigned m = v >> 20;
      int p = atomicAdd(&cursorD[d], 1);
      csrD[p] = (unsigned)s | (m << 20);
    }
  }
}

// ---------- dinv from int counts ----------
__global__ void dinv_k(const int* __restrict__ cnt, float* __restrict__ dinv, int nN)
{
  int i = blockIdx.x * blockDim.x + threadIdx.x;
  int tot = 4 * nN;
  if (i < tot) {
    float base = (i < nN) ? 1.f : 2.f;  // block0: +self ; replicas: +identity edge +self
    dinv[i] = 1.f / sqrtf((float)cnt[i] + base);
  }
}

// ---------- fused CSR gather + GCN finish (wave per destination node) ----------
// inner loop 4x-unrolled: 4 shfls + 4 independent row loads in flight.
template<bool L0, bool RELU>
__global__ void gather_finish_k(const int* __restrict__ rowoff, const unsigned* __restrict__ csr,
                                const float* __restrict__ xws, const float* __restrict__ xw,
                                const float* __restrict__ dinv, const float* __restrict__ bias,
                                float* __restrict__ out, int nN)
{
  const int lane = threadIdx.x & 63;
  const int wib  = threadIdx.x >> 6;
  const int wpb  = blockDim.x >> 6;
  const float b = bias[lane];
  for (int d = blockIdx.x * wpb + wib; d < nN; d += gridDim.x * wpb) {
    const int start = rowoff[d], end = rowoff[d + 1];
    float a0 = 0.f, a1 = 0.f, a2 = 0.f, a3 = 0.f;
    for (int base = start; base < end; base += 64) {
      const int nrem = end - base;
      unsigned p = (lane < nrem) ? csr[base + lane] : 0u;
      const int cntj = nrem < 64 ? nrem : 64;
      int j = 0;
      for (; j + 4 <= cntj; j += 4) {
        const unsigned pj0 = (unsigned)__shfl((int)p, j + 0);
        const unsigned pj1 = (unsigned)__shfl((int)p, j + 1);
        const unsigned pj2 = (unsigned)__shfl((int)p, j + 2);
        const unsigned pj3 = (unsigned)__shfl((int)p, j + 3);
        const float v0 = xws[(size_t)(pj0 & 0xFFFFFu) * FDIM + lane];
        const float v1 = xws[(size_t)(pj1 & 0xFFFFFu) * FDIM + lane];
        const float v2 = xws[(size_t)(pj2 & 0xFFFFFu) * FDIM + lane];
        const float v3 = xws[(size_t)(pj3 & 0xFFFFFu) * FDIM + lane];
        a0 += v0;
        if (pj0 & 0x100000u) a1 += v0;
        if (pj0 & 0x200000u) a2 += v0;
        if (pj0 & 0x400000u) a3 += v0;
        a0 += v1;
        if (pj1 & 0x100000u) a1 += v1;
        if (pj1 & 0x200000u) a2 += v1;
        if (pj1 & 0x400000u) a3 += v1;
        a0 += v2;
        if (pj2 & 0x100000u) a1 += v2;
        if (pj2 & 0x200000u) a2 += v2;
        if (pj2 & 0x400000u) a3 += v2;
        a0 += v3;
        if (pj3 & 0x100000u) a1 += v3;
        if (pj3 & 0x200000u) a2 += v3;
        if (pj3 & 0x400000u) a3 += v3;
      }
      for (; j < cntj; ++j) {
        const unsigned pj = (unsigned)__shfl((int)p, j);
        const float v = xws[(size_t)(pj & 0xFFFFFu) * FDIM + lane];
        a0 += v;
        if (pj & 0x100000u) a1 += v;
        if (pj & 0x200000u) a2 += v;
        if (pj & 0x400000u) a3 += v;
      }
    }
    const float di0 = dinv[d];
    const float xs  = xws[(size_t)d * FDIM + lane];
    const float xb0 = xw[(size_t)d * FDIM + lane];

    float r0 = (a0 + xs) * di0 + b;
    if (RELU) r0 = fmaxf(r0, 0.f);
    out[(size_t)d * FDIM + lane] = r0;

#pragma unroll
    for (int t = 1; t <= 3; ++t) {
      const float at = (t == 1) ? a1 : (t == 2) ? a2 : a3;
      const float dit = dinv[t * nN + d];
      const float self = L0 ? xb0 : xw[((size_t)t * nN + d) * FDIM + lane];
      float r = (at + xs + self * dit) * dit + b;
      if (RELU) r = fmaxf(r, 0.f);
      out[((size_t)t * nN + d) * FDIM + lane] = r;
    }
  }
}

// ---------- hyper[j,:] += x2_b0[i,:] where H[i,j] > 0 (LDS-accumulated) ----------
__global__ void hyper_k(const float* __restrict__ H, const float* __restrict__ x2,
                        float* __restrict__ hyper, int nN)
{
  __shared__ float hl[NSDIM * FDIM];
  for (int i = threadIdx.x; i < NSDIM * FDIM; i += blockDim.x) hl[i] = 0.f;
  __syncthreads();
  const int lane = threadIdx.x & 63;
  const int wib  = threadIdx.x >> 6;
  const int wpb  = blockDim.x >> 6;
  for (int i = blockIdx.x * wpb + wib; i < nN; i += gridDim.x * wpb) {
    float hv = H[(size_t)i * NSDIM + lane];
    unsigned long long ball = __ballot(hv > 0.f);
    float x = x2[(size_t)i * FDIM + lane];
    while (ball) {
      int j = __ffsll((unsigned long long)ball) - 1;
      ball &= ball - 1;
      atomicAdd(&hl[j * FDIM + lane], x);
    }
  }
  __syncthreads();
  for (int i = threadIdx.x; i < NSDIM * FDIM; i += blockDim.x) {
    float v = hl[i];
    if (v != 0.f) atomicAdd(&hyper[i], v);
  }
}

// ---------- hyper -> out1 + transposed copy for dots ----------
__global__ void hfin_k(const float* __restrict__ hyper, float* __restrict__ out1,
                       float* __restrict__ hyperT)
{
  int idx = blockIdx.x * blockDim.x + threadIdx.x;
  if (idx < NSDIM * FDIM) {
    float v = hyper[idx];
    out1[idx] = v;
    int j = idx >> 6, k = idx & 63;
    hyperT[k * NSDIM + j] = v;
  }
}

// ---------- coalesced per-column histogram: lane = column ----------
__global__ void colhist_k(const float* __restrict__ H, int* __restrict__ hist, int nN)
{
  const int lane = threadIdx.x & 63;
  const int wid  = blockIdx.x * (blockDim.x >> 6) + (threadIdx.x >> 6);
  const int nw   = gridDim.x * (blockDim.x >> 6);
  int c0 = 0, c1 = 0, c2 = 0, c3 = 0, c4 = 0;
  for (int i = wid; i < nN; i += nw) {
    const int v = (int)H[(size_t)i * NSDIM + lane];
    c0 += (v == 0); c1 += (v == 1); c2 += (v == 2); c3 += (v == 3); c4 += (v == 4);
  }
  if (c0) atomicAdd(&hist[0 * NSDIM + lane], c0);
  if (c1) atomicAdd(&hist[1 * NSDIM + lane], c1);
  if (c2) atomicAdd(&hist[2 * NSDIM + lane], c2);
  if (c3) atomicAdd(&hist[3 * NSDIM + lane], c3);
  if (c4) atomicAdd(&hist[4 * NSDIM + lane], c4);
}

// ---------- cmax/cden from histogram (64 threads) ----------
__global__ void colfin_k(const int* __restrict__ hist, float* __restrict__ cmax,
                         float* __restrict__ cden)
{
  const int j = threadIdx.x;
  if (j < NSDIM) {
    const int s0 = hist[j], s1 = hist[NSDIM + j], s2 = hist[2 * NSDIM + j];
    const int s3 = hist[3 * NSDIM + j], s4 = hist[4 * NSDIM + j];
    int m = 0;
    if (s1 > 0) m = 1;
    if (s2 > 0) m = 2;
    if (s3 > 0) m = 3;
    if (s4 > 0) m = 4;
    float den = 0.f;
    den += (float)s0 * expf((float)(0 - m));
    den += (float)s1 * expf((float)(1 - m));
    den += (float)s2 * expf((float)(2 - m));
    den += (float)s3 * expf((float)(3 - m));
    den += (float)s4 * expf((float)(4 - m));
    cmax[j] = (float)m;
    cden[j] = den;
  }
}

__global__ void hsoft_k(const float* __restrict__ H, const float* __restrict__ cmax,
                        const float* __restrict__ cden, float* __restrict__ out0, int nN)
{
  int idx = blockIdx.x * blockDim.x + threadIdx.x;
  int tot = nN * NSDIM;
  if (idx < tot) {
    int j = idx & (NSDIM - 1);
    out0[idx] = expf(H[idx] - cmax[j]) / cden[j];
  }
}

// ---------- host ----------
extern "C" void kernel_launch(void* const* d_in, const int* in_sizes, int n_in,
                              void* d_out, int out_size, void* d_ws, size_t ws_size,
                              hipStream_t stream)
{
  const int* edge_index = (const int*)d_in[0];
  const float* features = (const float*)d_in[1];
  const float* W_lin    = (const float*)d_in[2];
  const float* b_lin    = (const float*)d_in[3];
  const float* gcn0_W   = (const float*)d_in[4];
  const float* gcn0_b   = (const float*)d_in[5];
  const float* gcn1_W   = (const float*)d_in[6];
  const float* gcn1_b   = (const float*)d_in[7];
  const float* lin1_W   = (const float*)d_in[8];
  const float* lin1_b   = (const float*)d_in[9];

  const int E = in_sizes[0] / 2;
  const int N = in_sizes[1] / FDIM;

  const int* src = edge_index;
  const int* dst = edge_index + E;

  // workspace layout
  float* ws    = (float*)d_ws;
  float* G     = ws;                                   // 3*N*F (dead after mask_cnt)
  int*   cnt   = (int*)(G + (size_t)TREP * N * FDIM);  // 4N
  float* dinv  = (float*)(cnt + (size_t)4 * N);        // 4N
  int*   cntS  = (int*)(dinv + (size_t)4 * N);         // N (also cursorS)
  int*   rowoffS = cntS + N;                           // N+64
  unsigned* slotsS = (unsigned*)(rowoffS + N + 64);    // E
  float* xw0   = (float*)(slotsS + E);                 // N*F
  float* bufA  = xw0 + (size_t)N * FDIM;               // 4N*F (x1 -> x2)
  float* bufB  = bufA + (size_t)4 * N * FDIM;          // 4N*F (xw1)
  float* Harr  = bufB + (size_t)4 * N * FDIM;          // N*NS
  float* hyper = Harr + (size_t)N * NSDIM;             // NS*F
  float* cmax  = hyper + NSDIM * FDIM;                 // NS
  float* cden  = cmax + NSDIM;                         // NS
  float* hyperT = cden + NSDIM;                        // NS*F
  int*   tilesum = (int*)(hyperT + NSDIM * FDIM);      // ntiles+1
  int*   tileoff = tilesum + ((N + 255) / 256 + 1);    // ntiles+1
  int*   hist    = tileoff + ((N + 255) / 256 + 1);    // 5*NSDIM

  // dst-CSR + scaled message table alias the (dead-after-mask) G region
  int* rowoffD     = (int*)G;                          // N+64
  int* cursorD     = rowoffD + (N + 64);               // N
  unsigned* csrD   = (unsigned*)(cursorD + N);         // E
  float* xws       = (float*)(csrD + E);               // N*F

  float* out0 = (float*)d_out;             // H_soft (N,NS)
  float* out1 = out0 + (size_t)N * NSDIM;  // hyper (NS,F)
  float* out2 = out1 + NSDIM * FDIM;       // dots (4N,NS)

  const int BLK = 256;
  const int WPB = BLK / 64;
  const int ntiles = (N + 255) / 256;
  auto wgrid = [](int items, int wpb) { return (items + wpb - 1) / wpb; };
  auto tgrid = [](int rows) { return (rows + 255) / 256; };

  // zero accumulators
  hipMemsetAsync(cnt, 0, (size_t)4 * N * sizeof(int), stream);
  hipMemsetAsync(cntS, 0, (size_t)N * sizeof(int), stream);
  hipMemsetAsync(Harr, 0, (size_t)N * NSDIM * sizeof(float), stream);
  hipMemsetAsync(hyper, 0, (size_t)NSDIM * FDIM * sizeof(float), stream);
  hipMemsetAsync(hist, 0, (size_t)5 * NSDIM * sizeof(int), stream);

  // 1) src-CSR build: counts -> parallel scan -> fill
  cntS_k<<<1024, BLK, 0, stream>>>(src, cntS, E);
  scanA_k<<<ntiles, 256, 0, stream>>>(cntS, rowoffS, tilesum, N);
  scanB_k<<<1, 256, 0, stream>>>(tilesum, tileoff, ntiles);
  scanC_k<<<ntiles, 256, 0, stream>>>(rowoffS, cntS, tileoff, N, ntiles); // cntS -> cursorS
  fillS_k<<<1024, BLK, 0, stream>>>(src, dst, cntS, slotsS, E);

  // 2) G = normf*trans - normt*f  (trans/norms never materialized)
  {
    dim3 g(tgrid(N), TREP);
    gmat_k<<<g, BLK, 0, stream>>>(features, W_lin, b_lin, G, N);
  }

  // 3) mask + degree counts (16 edges/wave main loop)
  mask_cnt_k<<<wgrid(N, WPB), BLK, 0, stream>>>(rowoffS, slotsS, G, features, cnt, N);

  // 4) dst-CSR build (G dead; rowoffD/cursorD/csrD/xws alias it)
  scanA_k<<<ntiles, 256, 0, stream>>>(cnt, rowoffD, tilesum, N);
  scanB_k<<<1, 256, 0, stream>>>(tilesum, tileoff, ntiles);
  scanC_k<<<ntiles, 256, 0, stream>>>(rowoffD, cursorD, tileoff, N, ntiles);
  fillD_k<<<wgrid(N, WPB), BLK, 0, stream>>>(rowoffS, slotsS, cursorD, csrD, N);

  // 5) dinv
  dinv_k<<<(4 * N + BLK - 1) / BLK, BLK, 0, stream>>>(cnt, dinv, N);

  // 6) xw0 = relu(features) @ gcn0_W ; fused xws = xw0 * dinv0
  gemm_k<true><<<tgrid(N), BLK, 0, stream>>>(features, gcn0_W, xw0, N, xws, dinv, N);

  // 7) gcn0 gather+finish -> x1 (relu'd) in bufA
  gather_finish_k<true, true><<<wgrid(N, WPB), BLK, 0, stream>>>(
      rowoffD, csrD, xws, xw0, dinv, gcn0_b, bufA, N);

  // 8) xw1 = x1 @ gcn1_W (4N rows); fused xws = xw1(block0) * dinv0
  gemm_k<false><<<tgrid(4 * N), BLK, 0, stream>>>(bufA, gcn1_W, bufB, 4 * N, xws, dinv, N);

  // 9) gcn1 gather+finish -> x2 in bufA (no relu)
  gather_finish_k<false, false><<<wgrid(N, WPB), BLK, 0, stream>>>(
      rowoffD, csrD, xws, bufB, dinv, gcn1_b, bufA, N);

  // 10) logits + argmax -> H counts
  logits_k<<<tgrid(4 * N), BLK, 0, stream>>>(bufA, lin1_W, lin1_b, Harr, 4 * N, N);

  // 11) hyper (LDS-accumulated) + out1 + transpose
  hyper_k<<<128, BLK, 0, stream>>>(Harr, bufA, hyper, N);
  hfin_k<<<(NSDIM * FDIM + BLK - 1) / BLK, BLK, 0, stream>>>(hyper, out1, hyperT);

  // 12) H softmax over axis 0 (coalesced histogram)
  colhist_k<<<256, BLK, 0, stream>>>(Harr, hist, N);
  colfin_k<<<1, 64, 0, stream>>>(hist, cmax, cden);
  hsoft_k<<<(N * NSDIM + BLK - 1) / BLK, BLK, 0, stream>>>(Harr, cmax, cden, out0, N);

  // 13) dots
  dots_k<<<tgrid(N), BLK, 0, stream>>>(features, hyperT, out2, N);
}